// Round 1
// baseline (109.166 us; speedup 1.0000x reference)
//
#include <hip/hip_runtime.h>
#include <math.h>

#define BATCH 8
#define BN    512          // rois per frame
#define NC    37           // classes incl. background
#define NFG   36           // foreground classes
#define FD    2048         // feature dim
#define NW    2            // waves (= independent problems) per nms block

// Output layout (flat float32 in d_out, reference return order):
//   cls_dets  [B, NFG, BN, 5]  -> 737280 floats at offset 0
//   kept_feats[B, BN, FD]      -> 8388608 floats at offset 737280
//   keep      [B, NFG, BN]     -> 147456 floats (0/1) at offset 9125888
// d_ws: keep_t [B, BN, NFG] bytes (147456 B) — transposed keep for feat_kernel.

// -------------------- Kernel 1: decode + compact + sort + greedy NMS --------
// 144 blocks x 128 threads; each WAVE owns one (batch, fg-class) problem.
// One block per CU (no tail round). No __syncthreads — each wave uses its own
// LDS slab; in-wave LDS RAW ordering comes from compiler lgkmcnt waits, with
// wave_barrier() pinning instruction order at phase boundaries.
__global__ __launch_bounds__(128) void nms_kernel(
    const float* __restrict__ rois,       // [B,BN,5] (bidx,x1,y1,x2,y2)
    const float* __restrict__ bbox_pred,  // [B,BN,4*NC]
    const float* __restrict__ scores,     // [B,BN,NC]
    const float* __restrict__ im_info,    // [B,3] (h,w,scale)
    float* __restrict__ cls_dets,         // [B,NFG,BN,5]
    float* __restrict__ keep_out,         // [B,NFG,BN]
    unsigned char* __restrict__ keep_t)   // [B,BN,NFG] bytes
{
    const int wid  = threadIdx.x >> 6;
    const int lane = threadIdx.x & 63;
    const int bc   = blockIdx.x * NW + wid;   // 0..287
    const int b    = bc / NFG;
    const int cc   = bc % NFG;   // 0..35
    const int c    = cc + 1;     // class index 1..36

    __shared__ float sb[NW][BN][4];    // decoded clipped boxes, original index
    __shared__ float sarea[NW][BN];    // areas, original index
    __shared__ float cscore[NW][BN];   // compacted scores
    __shared__ int   cn[NW][BN];       // compacted original indices
    __shared__ float kflag[NW][BN];    // 0 = not kept; score = kept
    __shared__ unsigned char srem[NW][BN];  // generic-path remaining flags

    const float xmax = im_info[b * 3 + 1] - 1.0f;
    const float ymax = im_info[b * 3 + 0] - 1.0f;
    const unsigned long long lmask_lt = (lane == 0) ? 0ull : ((1ull << lane) - 1ull);

    // ---- prefetch everything (independent loads, one latency round) --------
    float  sc[8];
    float4 bp[8];                 // bbox_pred[..., 4c:4c+4] (16B-aligned)
    float  rx1[8], ry1[8], rx2[8], ry2[8];
#pragma unroll
    for (int r = 0; r < 8; ++r) {
        const int n = r * 64 + lane;
        sc[r] = scores[(size_t)(b * BN + n) * NC + c];
        bp[r] = *(const float4*)(bbox_pred + (size_t)(b * BN + n) * (4 * NC) + 4 * c);
        const float* rr = rois + (size_t)(b * BN + n) * 5;
        rx1[r] = rr[1]; ry1[r] = rr[2]; rx2[r] = rr[3]; ry2[r] = rr[4];
        kflag[wid][n] = 0.0f;
    }

    // ---- decode + clip ALL boxes (VALU is free at this occupancy) ----------
#pragma unroll
    for (int r = 0; r < 8; ++r) {
        const int n = r * 64 + lane;
        const float w  = rx2[r] - rx1[r];
        const float h  = ry2[r] - ry1[r];
        const float cx = rx1[r] + 0.5f * w;
        const float cy = ry1[r] + 0.5f * h;
        const float px = (bp[r].x * 0.1f) * w + cx;
        const float py = (bp[r].y * 0.1f) * h + cy;
        const float pw = expf(bp[r].z * 0.2f) * w;
        const float ph = expf(bp[r].w * 0.2f) * h;
        const float bx1 = fminf(fmaxf(px - 0.5f * pw, 0.0f), xmax);
        const float by1 = fminf(fmaxf(py - 0.5f * ph, 0.0f), ymax);
        const float bx2 = fminf(fmaxf(px + 0.5f * pw, 0.0f), xmax);
        const float by2 = fminf(fmaxf(py + 0.5f * ph, 0.0f), ymax);
        sb[wid][n][0] = bx1; sb[wid][n][1] = by1;
        sb[wid][n][2] = bx2; sb[wid][n][3] = by2;
        sarea[wid][n] = (bx2 - bx1) * (by2 - by1);
    }

    // ---- compact valid (score > 0.1) ---------------------------------------
    int base = 0;
#pragma unroll
    for (int r = 0; r < 8; ++r) {
        const int n = r * 64 + lane;
        const bool valid = sc[r] > 0.1f;
        const unsigned long long m = __ballot(valid);
        if (valid) {
            const int pos = base + __popcll(m & lmask_lt);
            cscore[wid][pos] = sc[r];
            cn[wid][pos] = n;
        }
        base += __popcll(m);
    }
    const int V = base;   // wave-uniform
    __builtin_amdgcn_wave_barrier();

    if (V <= 64) {
        // -------- fast path: register bitonic sort + masked greedy ----------
        float key; int id;
        if (lane < V) { key = cscore[wid][lane]; id = cn[wid][lane]; }
        else          { key = -INFINITY;         id = BN + lane; }
        // bitonic sort 64 lanes: (score desc, index asc)
#pragma unroll
        for (int k = 2; k <= 64; k <<= 1) {
#pragma unroll
            for (int j = k >> 1; j > 0; j >>= 1) {
                const float ok = __shfl_xor(key, j);
                const int   oi = __shfl_xor(id, j);
                const bool is_lower   = (lane & j) == 0;
                const bool dir_desc   = (lane & k) == 0;
                const bool mine_first = (key > ok) || (key == ok && id < oi);
                bool take = mine_first ^ is_lower;
                if (!dir_desc) take = !take;
                if (take) { key = ok; id = oi; }
            }
        }
        // fetch my sorted box
        float x1 = 0, y1 = 0, x2 = 0, y2 = 0, ar = 0;
        if (lane < V) {
            x1 = sb[wid][id][0]; y1 = sb[wid][id][1];
            x2 = sb[wid][id][2]; y2 = sb[wid][id][3];
            ar = sarea[wid][id];
        }
        // pipelined pass: column mask = which earlier boxes would suppress me
        unsigned long long colmask = 0;
        for (int i = 0; i < V; ++i) {
            const float ax1 = __shfl(x1, i);
            const float ay1 = __shfl(y1, i);
            const float ax2 = __shfl(x2, i);
            const float ay2 = __shfl(y2, i);
            const float aar = __shfl(ar, i);
            const float ix1 = fmaxf(ax1, x1);
            const float iy1 = fmaxf(ay1, y1);
            const float ix2 = fminf(ax2, x2);
            const float iy2 = fminf(ay2, y2);
            const float iw = fmaxf(ix2 - ix1, 0.0f);
            const float ih = fmaxf(iy2 - iy1, 0.0f);
            const float inter = iw * ih;
            const float iou = inter / (aar + ar - inter + 1e-9f);
            if ((iou > 0.4f) && (i < lane)) colmask |= (1ull << i);
        }
        // serial resolve: one ballot per surviving box
        unsigned long long rem = (V == 64) ? ~0ull : ((1ull << V) - 1ull);
        for (int i = 0; i < V; ++i) {
            if (!((rem >> i) & 1ull)) continue;        // wave-uniform
            rem &= ~__ballot((colmask >> i) & 1ull);
        }
        if (lane < V && ((rem >> lane) & 1ull)) {
            kflag[wid][id] = key;             // kept: record score by original index
        }
    } else {
        // -------- generic path (V > 64): LDS bitonic + LDS greedy -----------
        int P = 64; while (P < V) P <<= 1;
        for (int i = lane; i < P; i += 64) {
            if (i >= V) { cscore[wid][i] = -INFINITY; cn[wid][i] = BN + i; }
            srem[wid][i] = (i < V) ? 1 : 0;
        }
        __builtin_amdgcn_wave_barrier();
        for (int k = 2; k <= P; k <<= 1) {
            for (int j = k >> 1; j > 0; j >>= 1) {
                __builtin_amdgcn_wave_barrier();
                for (int i = lane; i < P; i += 64) {
                    const int ixj = i ^ j;
                    if (ixj > i) {
                        const float ka = cscore[wid][i], kb = cscore[wid][ixj];
                        const int   ia = cn[wid][i],     ib = cn[wid][ixj];
                        const bool a_first = (ka > kb) || (ka == kb && ia < ib);
                        const bool up = ((i & k) == 0);
                        if (up ? !a_first : a_first) {
                            cscore[wid][i] = kb; cscore[wid][ixj] = ka;
                            cn[wid][i] = ib;     cn[wid][ixj] = ia;
                        }
                    }
                }
            }
        }
        __builtin_amdgcn_wave_barrier();
        for (int i = 0; i < V; ++i) {
            __builtin_amdgcn_wave_barrier();
            if (!srem[wid][i]) continue;
            const int   ni  = cn[wid][i];
            const float ax1 = sb[wid][ni][0], ay1 = sb[wid][ni][1];
            const float ax2 = sb[wid][ni][2], ay2 = sb[wid][ni][3];
            const float aar = sarea[wid][ni];
            for (int jj = lane; jj < V; jj += 64) {
                if (jj > i && srem[wid][jj]) {
                    const int nj = cn[wid][jj];
                    const float ix1 = fmaxf(ax1, sb[wid][nj][0]);
                    const float iy1 = fmaxf(ay1, sb[wid][nj][1]);
                    const float ix2 = fminf(ax2, sb[wid][nj][2]);
                    const float iy2 = fminf(ay2, sb[wid][nj][3]);
                    const float iw = fmaxf(ix2 - ix1, 0.0f);
                    const float ih = fmaxf(iy2 - iy1, 0.0f);
                    const float inter = iw * ih;
                    const float iou = inter / (aar + sarea[wid][nj] - inter + 1e-9f);
                    if (iou > 0.4f) srem[wid][jj] = 0;
                }
            }
        }
        __builtin_amdgcn_wave_barrier();
        for (int i = lane; i < V; i += 64) {
            if (srem[wid][i]) kflag[wid][cn[wid][i]] = cscore[wid][i];
        }
    }
    __builtin_amdgcn_wave_barrier();

    // ---- unified output pass: every (n) written exactly once ----
    const size_t rowbase = (size_t)(b * NFG + cc) * BN;
#pragma unroll
    for (int r = 0; r < 8; ++r) {
        const int n = r * 64 + lane;
        const float s = kflag[wid][n];
        const bool kept = s > 0.0f;
        keep_out[rowbase + n] = kept ? 1.0f : 0.0f;
        keep_t[(size_t)(b * BN + n) * NFG + cc] = kept ? 1 : 0;
        float* cd = cls_dets + (rowbase + n) * 5;
        cd[0] = kept ? sb[wid][n][0] : 0.0f;
        cd[1] = kept ? sb[wid][n][1] : 0.0f;
        cd[2] = kept ? sb[wid][n][2] : 0.0f;
        cd[3] = kept ? sb[wid][n][3] : 0.0f;
        cd[4] = kept ? s : 0.0f;
    }
}

// -------------------- Kernel 2: kept_feats = any(keep_t[bn,:]) ? feats : 0 --
// One block per (b, n); 512 threads = exactly one float4 per thread.
// Per-WAVE any-check via ballot (lanes 0..35 each read one keep byte; L1
// absorbs the 8x redundancy) — no LDS, no __syncthreads on the critical path.
__global__ __launch_bounds__(512) void feat_kernel(
    const float* __restrict__ feats,            // [B,BN,FD]
    const unsigned char* __restrict__ keep_t,   // [B,BN,NFG] bytes
    float* __restrict__ out_feats)              // [B,BN,FD]
{
    const int bn   = blockIdx.x;
    const int lane = threadIdx.x & 63;

    unsigned char kb = 0;
    if (lane < NFG) kb = keep_t[(size_t)bn * NFG + lane];
    const bool any = __ballot(kb != 0) != 0ull;

    const int t = threadIdx.x;                       // 0..511 == FD/4
    const float4* src = (const float4*)(feats + (size_t)bn * FD);
    float4*       dst = (float4*)(out_feats + (size_t)bn * FD);
    if (any) {
        dst[t] = src[t];
    } else {
        dst[t] = make_float4(0.f, 0.f, 0.f, 0.f);
    }
}

extern "C" void kernel_launch(void* const* d_in, const int* in_sizes, int n_in,
                              void* d_out, int out_size, void* d_ws, size_t ws_size,
                              hipStream_t stream) {
    const float* rois      = (const float*)d_in[0];  // [8,512,5]
    const float* bbox_pred = (const float*)d_in[1];  // [8,512,148]
    const float* scores    = (const float*)d_in[2];  // [8,512,37]
    const float* im_info   = (const float*)d_in[3];  // [8,3]
    const float* feats     = (const float*)d_in[4];  // [8,512,2048]

    float* out        = (float*)d_out;
    float* cls_dets   = out;                                     // 737280
    float* kept_feats = out + (size_t)BATCH * NFG * BN * 5;      // 8388608
    float* keep_out   = kept_feats + (size_t)BATCH * BN * FD;    // 147456

    unsigned char* keep_t = (unsigned char*)d_ws;  // [B,BN,NFG] bytes, fully rewritten

    nms_kernel<<<(BATCH * NFG) / NW, 64 * NW, 0, stream>>>(
        rois, bbox_pred, scores, im_info, cls_dets, keep_out, keep_t);
    feat_kernel<<<BATCH * BN, 512, 0, stream>>>(feats, keep_t, kept_feats);
}